// Round 14
// baseline (751.633 us; speedup 1.0000x reference)
//
#include <hip/hip_runtime.h>

typedef float fv2 __attribute__((ext_vector_type(2)));
typedef float fv4 __attribute__((ext_vector_type(4)));
typedef _Float16 hfv8 __attribute__((ext_vector_type(8)));
typedef unsigned short u16v4 __attribute__((ext_vector_type(4)));
typedef unsigned short u16v8 __attribute__((ext_vector_type(8)));
typedef unsigned int u32v4 __attribute__((ext_vector_type(4)));

#define B_DIM 4
#define L_DIM 8192
#define D_DIM 1024
#define H_NUM 16
#define NSEG 16
#define SEG_S 512
#define M_TOK (B_DIM * L_DIM)  // 32768

__device__ __forceinline__ unsigned short f2h(float f) {
  return __builtin_bit_cast(unsigned short, (_Float16)f);  // v_cvt_f16_f32 RNE
}
__device__ __forceinline__ float h2f(unsigned short u) {
  return (float)__builtin_bit_cast(_Float16, u);
}
// packed fp16 pair: hi in low 16 bits, lo residual in high 16 bits
__device__ __forceinline__ unsigned packh2(float v) {
  const _Float16 h = (_Float16)v;
  const unsigned short lb = __builtin_bit_cast(unsigned short, (_Float16)(v - (float)h));
  return (unsigned)__builtin_bit_cast(unsigned short, h) | ((unsigned)lb << 16);
}

// unpack 8 packed pairs (2 x u32v4) -> u16v8 hi plane and u16v8 lo plane
__device__ __forceinline__ void unpack8(u32v4 a, u32v4 b, u16v8& hi8, u16v8& lo8) {
  u32v4 hi, lo;
  hi[0] = __builtin_amdgcn_perm(a[1], a[0], 0x05040100u);
  hi[1] = __builtin_amdgcn_perm(a[3], a[2], 0x05040100u);
  hi[2] = __builtin_amdgcn_perm(b[1], b[0], 0x05040100u);
  hi[3] = __builtin_amdgcn_perm(b[3], b[2], 0x05040100u);
  lo[0] = __builtin_amdgcn_perm(a[1], a[0], 0x07060302u);
  lo[1] = __builtin_amdgcn_perm(a[3], a[2], 0x07060302u);
  lo[2] = __builtin_amdgcn_perm(b[1], b[0], 0x07060302u);
  lo[3] = __builtin_amdgcn_perm(b[3], b[2], 0x07060302u);
  hi8 = __builtin_bit_cast(u16v8, hi);
  lo8 = __builtin_bit_cast(u16v8, lo);
}
// hi plane only (4 perms) — used for K staging in attn
__device__ __forceinline__ u16v8 hi8of(u32v4 a, u32v4 b) {
  u32v4 hi;
  hi[0] = __builtin_amdgcn_perm(a[1], a[0], 0x05040100u);
  hi[1] = __builtin_amdgcn_perm(a[3], a[2], 0x05040100u);
  hi[2] = __builtin_amdgcn_perm(b[1], b[0], 0x05040100u);
  hi[3] = __builtin_amdgcn_perm(b[3], b[2], 0x05040100u);
  return __builtin_bit_cast(u16v8, hi);
}

// ---------------- fp32 -> single fp16 plane (weights and x) ----------------
__global__ __launch_bounds__(256) void conv_w16(
    const float* __restrict__ in, unsigned short* __restrict__ outp, int n4) {
  int i = blockIdx.x * 256 + threadIdx.x;
  const int stride = gridDim.x * 256;
  for (; i < n4; i += stride) {
    fv4 v = reinterpret_cast<const fv4*>(in)[i];
    u16v4 p;
#pragma unroll
    for (int j = 0; j < 4; ++j) p[j] = f2h(v[j]);
    reinterpret_cast<u16v4*>(outp)[i] = p;
  }
}

// ---------------- C = A @ B^T, fp16 MFMA, gload_lds, 3-buf counted-vmcnt ----------------
// A: [M][K] fp16. B: [NTILES*128][K] fp16. Per phase: vmcnt(4) waits only the stage
// issued 2 phases ago (T4 — never drain in main loop); STAGE(t+2) into the buffer
// read at t-1 (barrier-protected). Swizzle: inverse-swz global source + swz ds_read.
// QKV=1: merged epilogue -> {Qp,Kp packed-pair | Vs fp16} per 1024-col group.
// QKV=0: fp32 C + bias.
template <int QKV>
__global__ __launch_bounds__(256, 3) void gemm_bt(
    const _Float16* __restrict__ A16, const _Float16* __restrict__ B16,
    float* __restrict__ C, const float* __restrict__ bias,
    unsigned* __restrict__ Qp, unsigned* __restrict__ Kp,
    unsigned short* __restrict__ Vs, int M, int NTILES, int K) {
  __shared__ _Float16 sA[3][4096];  // [buf][128 rows x 32 k]
  __shared__ _Float16 sB[3][4096];
  const int tid = threadIdx.x;
  const int lane = tid & 63;
  const int wv = tid >> 6;
  const int wr = wv >> 1, wc = wv & 1;
  const int g = lane >> 4, ln16 = lane & 15;

  // T1 XCD swizzle: all NTILES N-tiles of one M-panel share one XCD.
  const int hw = blockIdx.x;
  const int xcd = hw & 7;
  const int rem = hw >> 3;
  const int ntile = rem % NTILES;
  const int yhi = rem / NTILES;         // 0..(M/128/8 - 1)
  const int mtile = yhi * 8 + xcd;
  const int mBase = mtile * 128;
  const int nBase = ntile * 128;

  // bias pre-loaded BEFORE any STAGE so loop vmcnt counts stay exact.
  const int ccol0 = nBase + wc * 64 + (lane & 15);
  float bv[4] = {};
  if (QKV == 0 && bias) {
#pragma unroll
    for (int j = 0; j < 4; ++j) bv[j] = bias[ccol0 + j * 16];
  }

  fv4 acc[4][4] = {};

  // staging: lane l -> row = wv*32 + i*16 + (l>>2); LDS chunk l&3 holds global
  // chunk (l&3) ^ sw(row), sw(row) = (row>>1)&3 = (l>>3)&3.
  const int srow = lane >> 2;
  const int cgx = ((lane & 3) ^ ((lane >> 3) & 3)) * 8;
  const long aStageBase = (long)(mBase + wv * 32 + srow) * K + cgx;
  const long bStageBase = (long)(nBase + wv * 32 + srow) * K + cgx;
  // frag reads: global chunk g of row lives at LDS chunk g ^ ((ln16>>1)&3)
  const int rgx = (g ^ ((ln16 >> 1) & 3)) * 8;
  const int arow0 = wr * 64 + ln16;
  const int brow0 = wc * 64 + ln16;

  auto STAGE = [&](int t, int bi) {
#pragma unroll
    for (int i = 0; i < 2; ++i) {
      __builtin_amdgcn_global_load_lds(
          (const __attribute__((address_space(1))) void*)(A16 + aStageBase + (long)i * 16 * K + t * 32),
          (__attribute__((address_space(3))) void*)&sA[bi][wv * 1024 + i * 512], 16, 0, 0);
      __builtin_amdgcn_global_load_lds(
          (const __attribute__((address_space(1))) void*)(B16 + bStageBase + (long)i * 16 * K + t * 32),
          (__attribute__((address_space(3))) void*)&sB[bi][wv * 1024 + i * 512], 16, 0, 0);
    }
  };
  auto COMPUTE = [&](int bi) {
    hfv8 fa[4], fb[4];
#pragma unroll
    for (int i = 0; i < 4; ++i) {
      fa[i] = *(const hfv8*)&sA[bi][(arow0 + i * 16) * 32 + rgx];
      fb[i] = *(const hfv8*)&sB[bi][(brow0 + i * 16) * 32 + rgx];
    }
#pragma unroll
    for (int i = 0; i < 4; ++i)
#pragma unroll
      for (int j = 0; j < 4; ++j)
        acc[i][j] = __builtin_amdgcn_mfma_f32_16x16x32_f16(fa[i], fb[j], acc[i][j], 0, 0, 0);
  };

  const int NT = K / 32;  // 32
  STAGE(0, 0);
  STAGE(1, 1);
  for (int t = 0; t < NT; ++t) {
    if (t < NT - 1)
      asm volatile("s_waitcnt vmcnt(4)" ::: "memory");  // stage t landed; t+1 in flight
    else
      asm volatile("s_waitcnt vmcnt(0)" ::: "memory");  // final: drain last stage
    __builtin_amdgcn_s_barrier();                        // all waves see buf[t%3]
    if (t + 2 < NT) STAGE(t + 2, (t + 2) % 3);           // buf read at t-1: safe
    COMPUTE(t % 3);
    asm volatile("s_waitcnt lgkmcnt(0)" ::: "memory");   // reads retired before next barrier
  }

  // C/D layout (m89, dtype-independent): col = lane&15, row = 4*(lane>>4) + reg
  const int crow0 = mBase + wr * 64 + ((lane >> 4) << 2);
  if (QKV) {
    const int which = nBase >> 10;            // 0=Q, 1=K, 2=V (uniform per block)
    const int colb = ccol0 & 1023;
    unsigned* dstp = (which == 0) ? Qp : Kp;
#pragma unroll
    for (int j = 0; j < 4; ++j) {
      const int col = colb + j * 16;
#pragma unroll
      for (int i = 0; i < 4; ++i) {
        const long rb = (long)(crow0 + i * 16) * 1024 + col;
#pragma unroll
        for (int r = 0; r < 4; ++r) {
          if (which < 2) dstp[rb + (long)r * 1024] = packh2(acc[i][j][r]);
          else Vs[rb + (long)r * 1024] = f2h(acc[i][j][r]);
        }
      }
    }
  } else {
#pragma unroll
    for (int j = 0; j < 4; ++j) {
      const int col = ccol0 + j * 16;
#pragma unroll
      for (int i = 0; i < 4; ++i) {
        const long rb = (long)(crow0 + i * 16) * 1024 + col;
#pragma unroll
        for (int r = 0; r < 4; ++r)
          C[rb + (long)r * 1024] = acc[i][j][r] + bv[j];
      }
    }
  }
}

// ---------------- per-(b,seg,h) outer products: U = akT.v, fp16 2-product ----------------
__global__ __launch_bounds__(256) void seg_outer_mfma(
    const unsigned* __restrict__ Kp, const unsigned short* __restrict__ V16,
    float* __restrict__ U, float* __restrict__ Zs) {
  __shared__ _Float16 sAh[64 * 64], sAl[64 * 64];  // akT [d][s]
  __shared__ _Float16 sVh[64 * 64];                // vT  [e][s]
  __shared__ float sZf[64];
  const int bid = blockIdx.x;  // b*256 + seg*16 + h
  const int b = bid >> 8, seg = (bid >> 4) & 15, h = bid & 15;
  const int tid = threadIdx.x;
  const int lane = tid & 63, w = tid >> 6;
  const int g = lane >> 4, ln16 = lane & 15;
  const long base = ((long)b * L_DIM + (long)seg * SEG_S) * D_DIM + h * 64;

  if (tid < 64) sZf[tid] = 0.f;
  fv4 acc[4] = {};
  float zacc = 0.f;
  const int strow = tid & 63;
  const int sg0 = (tid >> 6) * 16;
  const int wsw = (strow & 7) << 3;
  const int rsw = (ln16 & 7) << 3;

  for (int c = 0; c < 8; ++c) {
    __syncthreads();
#pragma unroll
    for (int jj = 0; jj < 2; ++jj) {
      u16v8 ah, al, vh;
#pragma unroll
      for (int i = 0; i < 8; ++i) {
        const long gidx = base + (long)(c * 64 + sg0 + jj * 8 + i) * D_DIM + strow;
        const unsigned ku = Kp[gidx];
        const float kv = h2f((unsigned short)(ku & 0xffffu)) +
                         h2f((unsigned short)(ku >> 16));
        const float a = kv > 0.f ? kv + 1.f : __expf(kv);
        zacc += a;
        const unsigned short hb = f2h(a);
        ah[i] = hb;
        al[i] = f2h(a - h2f(hb));
        vh[i] = V16[gidx];
      }
      const int col = (sg0 + jj * 8) ^ wsw;
      *(u16v8*)&sAh[strow * 64 + col] = ah;
      *(u16v8*)&sAl[strow * 64 + col] = al;
      *(u16v8*)&sVh[strow * 64 + col] = vh;
    }
    __syncthreads();
#pragma unroll
    for (int kf = 0; kf < 2; ++kf) {
      const int so = (kf * 32 + g * 8) ^ rsw;
      hfv8 aH = *(const hfv8*)&sAh[(w * 16 + ln16) * 64 + so];
      hfv8 aL = *(const hfv8*)&sAl[(w * 16 + ln16) * 64 + so];
#pragma unroll
      for (int et = 0; et < 4; ++et) {
        hfv8 bH = *(const hfv8*)&sVh[(et * 16 + ln16) * 64 + so];
        acc[et] = __builtin_amdgcn_mfma_f32_16x16x32_f16(aH, bH, acc[et], 0, 0, 0);
        acc[et] = __builtin_amdgcn_mfma_f32_16x16x32_f16(aL, bH, acc[et], 0, 0, 0);
      }
    }
  }
  atomicAdd(&sZf[strow], zacc);
  __syncthreads();

  const long ub = (long)bid * 4096;
#pragma unroll
  for (int et = 0; et < 4; ++et)
#pragma unroll
    for (int r = 0; r < 4; ++r)
      U[ub + (long)(w * 16 + g * 4 + r) * 64 + et * 16 + ln16] = acc[et][r];
  if (tid < 64) Zs[(long)bid * 64 + tid] = sZf[tid];
}

// ---------------- exclusive prefix over segments (per b,h) ----------------
__global__ __launch_bounds__(256) void seg_prefix(
    const float* __restrict__ U, const float* __restrict__ Zs,
    float* __restrict__ Mem, float* __restrict__ Zp) {
  const int bh = blockIdx.x;
  const int b = bh >> 4, h = bh & 15;
  const int jc = blockIdx.y;
  const int tid = threadIdx.x;
  for (int j = jc * 512 + tid; j < jc * 512 + 512; j += 256) {
    float run = 0.f;
#pragma unroll
    for (int t = 0; t < NSEG; ++t) {
      const long idx = ((long)(b * 256 + t * 16 + h)) * 4096 + j;
      Mem[idx] = run;
      run += U[idx];
    }
  }
  if (jc == 0 && tid < 64) {
    float run = 0.f;
#pragma unroll
    for (int t = 0; t < NSEG; ++t) {
      const long idx = ((long)(b * 256 + t * 16 + h)) * 64 + tid;
      Zp[idx] = run;
      run += Zs[idx];
    }
  }
}

// ---------------- MFMA segment attention, fp16; out = single fp16 ----------------
__global__ __launch_bounds__(512, 4) void attn_seg_mfma(
    const unsigned* __restrict__ Qp, const unsigned* __restrict__ Kp,
    const unsigned short* __restrict__ V16, const int* __restrict__ mask,
    const float* __restrict__ Mem, const float* __restrict__ Zp,
    const float* __restrict__ betas, unsigned short* __restrict__ Op16, int b) {
  __shared__ _Float16 sKh[64 * 72];   // K chunk [key][d] hi; later Mem^T [e][d] hi
  __shared__ _Float16 sVTh[64 * 64];  // V^T [e][key], swizzled
  __shared__ _Float16 sP[8][16 * 72]; // per-wave P fp16 [q][key]
  __shared__ float sMadd[64], sZ[64], sGate[64];

  const int bx = (blockIdx.x & 7) * 128 + (blockIdx.x >> 3);  // T1 bijective
  const int qblk = bx & 3, h = (bx >> 2) & 15, seg = bx >> 6;
  const int shb = b * 256 + seg * 16 + h;
  const int tid = threadIdx.x;
  const int lane = tid & 63, w = tid >> 6;
  const int g = lane >> 4, ln16 = lane & 15;
  const int rsw = (ln16 & 7) << 3;

  const int qglob = b * L_DIM + seg * SEG_S + qblk * 128 + w * 16 + ln16;
  const long qbase = (long)qglob * D_DIM + h * 64;
  hfv8 qh[2], ql[2];
#pragma unroll
  for (int dt = 0; dt < 2; ++dt) {
    u32v4 a = *(const u32v4*)&Qp[qbase + dt * 32 + g * 8];
    u32v4 bb = *(const u32v4*)&Qp[qbase + dt * 32 + g * 8 + 4];
    u16v8 hi8, lo8;
    unpack8(a, bb, hi8, lo8);
    qh[dt] = __builtin_bit_cast(hfv8, hi8);
    ql[dt] = __builtin_bit_cast(hfv8, lo8);
  }

  fv4 O[4] = {};
  float m_run = -1e30f, l_run = 0.f;
  const long kvbase0 = ((long)b * L_DIM + (long)seg * SEG_S) * D_DIM + h * 64;

  for (int c = 0; c < 8; ++c) {
    __syncthreads();
    {  // stage K hi [64 key][64 d]
      const int row = tid >> 3, d0 = (tid & 7) * 8;
      const long ga = kvbase0 + (long)(c * 64 + row) * D_DIM + d0;
      u32v4 a = *(const u32v4*)&Kp[ga], bb = *(const u32v4*)&Kp[ga + 4];
      *(u16v8*)&sKh[row * 72 + d0] = hi8of(a, bb);
    }
    {  // stage V^T [64 e][64 key], XOR-swizzled
      const int e = tid & 63, kg = (tid >> 6) * 8;
      u16v8 hv;
#pragma unroll
      for (int j = 0; j < 8; ++j)
        hv[j] = V16[kvbase0 + (long)(c * 64 + kg + j) * D_DIM + e];
      *(u16v8*)&sVTh[e * 64 + (kg ^ ((e & 7) << 3))] = hv;
    }
    if (tid < 64)
      sMadd[tid] = (mask[b * L_DIM + seg * SEG_S + c * 64 + tid] == 0) ? -1e9f : 0.f;
    __syncthreads();

    fv4 madd[4];
#pragma unroll
    for (int kt = 0; kt < 4; ++kt) madd[kt] = *(const fv4*)&sMadd[kt * 16 + g * 4];

    // S^T = K_hi . (Q_hi + Q_lo)
    fv4 sc[4];
#pragma unroll
    for (int kt = 0; kt < 4; ++kt) {
      const int ro = (kt * 16 + ln16) * 72 + g * 8;
      hfv8 kh0 = *(const hfv8*)&sKh[ro], kh1 = *(const hfv8*)&sKh[ro + 32];
      fv4 s = {};
      s = __builtin_amdgcn_mfma_f32_16x16x32_f16(kh0, qh[0], s, 0, 0, 0);
      s = __builtin_amdgcn_mfma_f32_16x16x32_f16(kh1, qh[1], s, 0, 0, 0);
      s = __builtin_amdgcn_mfma_f32_16x16x32_f16(kh0, ql[0], s, 0, 0, 0);
      s = __builtin_amdgcn_mfma_f32_16x16x32_f16(kh1, ql[1], s, 0, 0, 0);
      sc[kt] = s;
    }
    // online softmax (defer-max THR=8)
    float pmax = -3.0e38f;
#pragma unroll
    for (int kt = 0; kt < 4; ++kt)
#pragma unroll
      for (int r = 0; r < 4; ++r) {
        const float v = __builtin_fmaf(sc[kt][r], 0.125f, madd[kt][r]);
        sc[kt][r] = v;
        pmax = fmaxf(pmax, v);
      }
    pmax = fmaxf(pmax, __shfl_xor(pmax, 16));
    pmax = fmaxf(pmax, __shfl_xor(pmax, 32));
    if (pmax > m_run + 8.f) {
      const float resc = __expf(m_run - pmax);
      l_run *= resc;
#pragma unroll
      for (int et = 0; et < 4; ++et)
#pragma unroll
        for (int r = 0; r < 4; ++r) O[et][r] *= resc;
      m_run = pmax;
    }
    float psum = 0.f;
#pragma unroll
    for (int kt = 0; kt < 4; ++kt) {
      u16v4 pv;
#pragma unroll
      for (int r = 0; r < 4; ++r) {
        const unsigned short hb = f2h(__expf(sc[kt][r] - m_run));
        pv[r] = hb;
        psum += h2f(hb);
      }
      *(u16v4*)&sP[w][ln16 * 72 + kt * 16 + g * 4] = pv;
    }
    psum += __shfl_xor(psum, 16);
    psum += __shfl_xor(psum, 32);
    l_run += psum;

    hfv8 pf0 = *(const hfv8*)&sP[w][ln16 * 72 + g * 8];
    hfv8 pf1 = *(const hfv8*)&sP[w][ln16 * 72 + 32 + g * 8];
    // O^T += V^T . P
#pragma unroll
    for (int et = 0; et < 4; ++et) {
      const int rb = (et * 16 + ln16) * 64;
      hfv8 vh0 = *(const hfv8*)&sVTh[rb + ((g * 8) ^ rsw)];
      hfv8 vh1 = *(const hfv8*)&sVTh[rb + ((g * 8 + 32) ^ rsw)];
      fv4 o = O[et];
      o = __builtin_amdgcn_mfma_f32_16x16x32_f16(vh0, pf0, o, 0, 0, 0);
      o = __builtin_amdgcn_mfma_f32_16x16x32_f16(vh1, pf1, o, 0, 0, 0);
      O[et] = o;
    }
  }

  // ---- memory-read term ----
  __syncthreads();
  {  // stage Mem^T hi [e][d] into sKh
    const int e2 = (tid & 31) * 2, d4 = (tid >> 5) * 4;
    const float* Memp = Mem + (long)shb * 4096;
    fv2 ld[4];
#pragma unroll
    for (int i = 0; i < 4; ++i) ld[i] = *(const fv2*)&Memp[(d4 + i) * 64 + e2];
#pragma unroll
    for (int je = 0; je < 2; ++je) {
      u16v4 hv;
#pragma unroll
      for (int i = 0; i < 4; ++i) hv[i] = f2h(ld[i][je]);
      *(u16v4*)&sKh[(e2 + je) * 72 + d4] = hv;
    }
  }
  if (tid < 64) {
    sZ[tid] = Zp[(long)shb * 64 + tid];
    sGate[tid] = 1.f / (1.f + __expf(-betas[h * 64 + tid]));
  }
  __syncthreads();

  // aq = elu(q)+1 split fp16; denom = aq . z (fp32)
  float dpart = 0.f;
#pragma unroll
  for (int dt = 0; dt < 2; ++dt) {
    u16v8 ah, al;
#pragma unroll
    for (int j = 0; j < 8; ++j) {
      const float x = (float)qh[dt][j] + (float)ql[dt][j];
      const float a = x > 0.f ? x + 1.f : __expf(x);
      dpart += a * sZ[dt * 32 + g * 8 + j];
      const unsigned short hb = f2h(a);
      ah[j] = hb;
      al[j] = f2h(a - h2f(hb));
    }
    qh[dt] = __builtin_bit_cast(hfv8, ah);
    ql[dt] = __builtin_bit_cast(hfv8, al);
  }
  dpart += __shfl_xor(dpart, 16);
  dpart += __shfl_xor(dpart, 32);
  const float invden = 1.f / (dpart + 1e-9f);
  const float invl = 1.f / l_run;

  const long obase = (long)qglob * D_DIM + h * 64;
#pragma unroll
  for (int et = 0; et < 4; ++et) {
    const int ro = (et * 16 + ln16) * 72 + g * 8;
    hfv8 mh0 = *(const hfv8*)&sKh[ro], mh1 = *(const hfv8*)&sKh[ro + 32];
    fv4 o = {};
    o = __builtin_amdgcn_mfma_f32_16x16x32_f16(mh0, qh[0], o, 0, 0, 0);
    o = __builtin_amdgcn_mfma_f32_16x16x32_f16(mh1, qh[1], o, 0, 0, 0);
    o = __builtin_amdgcn_mfma_f32_16x16x32_f16(mh0, ql[0], o, 0, 0, 0);
    o = __builtin_amdgcn_mfma_f32_16x16x32_f16(mh1, ql[1], o, 0, 0, 0);
    const fv4 gt = *(const fv4*)&sGate[et * 16 + g * 4];
    u16v4 st;
#pragma unroll
    for (int r = 0; r < 4; ++r) {
      const float att = gt[r] * o[r] * invden + (1.f - gt[r]) * O[et][r] * invl;
      st[r] = f2h(att);
    }
    *(u16v4*)&Op16[obase + et * 16 + g * 4] = st;
  }
}

// ---------------- host launch ----------------
extern "C" void kernel_launch(void* const* d_in, const int* in_sizes, int n_in,
                              void* d_out, int out_size, void* d_ws, size_t ws_size,
                              hipStream_t stream) {
  (void)in_sizes; (void)n_in; (void)out_size;
  const float* x     = (const float*)d_in[0];
  const int*   mask  = (const int*)d_in[1];
  const float* wq    = (const float*)d_in[2];
  const float* wk    = (const float*)d_in[3];
  const float* wv    = (const float*)d_in[4];
  const float* wo    = (const float*)d_in[5];
  const float* wob   = (const float*)d_in[6];
  const float* betas = (const float*)d_in[7];
  float* out = (float*)d_out;

  const size_t TOK = (size_t)M_TOK * D_DIM;  // 33.5M elements
  char* ws = (char*)d_ws;
  size_t off = 0;
  auto alloc = [&](size_t bytes) {
    char* p = ws + off;
    off += (bytes + 255) & ~(size_t)255;
    return p;
  };
  // merged qkv weights [3072][1024] fp16, then wo fp16
  unsigned short* wqkv16 = (unsigned short*)alloc((size_t)3 * D_DIM * D_DIM * 2);
  unsigned short* wo16   = (unsigned short*)alloc((size_t)D_DIM * D_DIM * 2);
  unsigned short* x16 = (unsigned short*)alloc(TOK * 2);  // 64 MiB
  unsigned* qp = (unsigned*)alloc(TOK * 4);               // 128 MiB (pairs)
  unsigned* kp = (unsigned*)alloc(TOK * 4);               // 128 MiB (pairs)
  unsigned short* vp16 = (unsigned short*)alloc(TOK * 2); // 64 MiB
  float* U   = (float*)alloc((size_t)B_DIM * NSEG * H_NUM * 4096 * 4);
  float* Mem = (float*)alloc((size_t)B_DIM * NSEG * H_NUM * 4096 * 4);
  float* Zs  = (float*)alloc((size_t)B_DIM * NSEG * H_NUM * 64 * 4);
  float* Zp  = (float*)alloc((size_t)B_DIM * NSEG * H_NUM * 64 * 4);
  unsigned short* att16 = x16;  // x16 dead after QKV GEMM — reuse

  if (off > ws_size) return;

  conv_w16<<<256, 256, 0, stream>>>(wq, wqkv16, D_DIM * D_DIM / 4);
  conv_w16<<<256, 256, 0, stream>>>(wk, wqkv16 + (size_t)D_DIM * D_DIM, D_DIM * D_DIM / 4);
  conv_w16<<<256, 256, 0, stream>>>(wv, wqkv16 + (size_t)2 * D_DIM * D_DIM, D_DIM * D_DIM / 4);
  conv_w16<<<256, 256, 0, stream>>>(wo, wo16, D_DIM * D_DIM / 4);
  conv_w16<<<2048, 256, 0, stream>>>(x, x16, (int)(TOK / 4));

  // merged QKV: N = 3072 (24 N-tiles), one dispatch
  const int qkvGrid = 24 * (M_TOK / 128);  // 6144, XCD-swizzled in-kernel
  gemm_bt<1><<<qkvGrid, 256, 0, stream>>>(
      (const _Float16*)x16, (const _Float16*)wqkv16, nullptr, nullptr,
      qp, kp, vp16, M_TOK, 24, D_DIM);

  seg_outer_mfma<<<B_DIM * NSEG * H_NUM, 256, 0, stream>>>(kp, vp16, U, Zs);
  seg_prefix<<<dim3(B_DIM * H_NUM, 8), 256, 0, stream>>>(U, Zs, Mem, Zp);

  for (int b = 0; b < B_DIM; ++b)
    attn_seg_mfma<<<NSEG * H_NUM * 4, 512, 0, stream>>>(qp, kp, vp16, mask, Mem, Zp,
                                                        betas, att16, b);

  const int oGrid = 8 * (M_TOK / 128);  // 2048
  gemm_bt<0><<<oGrid, 256, 0, stream>>>(
      (const _Float16*)att16, (const _Float16*)wo16, out, wob,
      nullptr, nullptr, nullptr, M_TOK, 8, D_DIM);
}

// Round 15
// 603.023 us; speedup vs baseline: 1.2464x; 1.2464x over previous
//
#include <hip/hip_runtime.h>

typedef float fv2 __attribute__((ext_vector_type(2)));
typedef float fv4 __attribute__((ext_vector_type(4)));
typedef _Float16 hfv8 __attribute__((ext_vector_type(8)));
typedef unsigned short u16v4 __attribute__((ext_vector_type(4)));
typedef unsigned short u16v8 __attribute__((ext_vector_type(8)));

#define B_DIM 4
#define L_DIM 8192
#define D_DIM 1024
#define H_NUM 16
#define NSEG 16
#define SEG_S 512
#define M_TOK (B_DIM * L_DIM)  // 32768

__device__ __forceinline__ unsigned short f2h(float f) {
  return __builtin_bit_cast(unsigned short, (_Float16)f);  // v_cvt_f16_f32 RNE
}
__device__ __forceinline__ float h2f(unsigned short u) {
  return (float)__builtin_bit_cast(_Float16, u);
}

// ---------------- fp32 -> fp16 (weights and x) ----------------
__global__ __launch_bounds__(256) void conv_w16(
    const float* __restrict__ in, unsigned short* __restrict__ outp, int n4) {
  int i = blockIdx.x * 256 + threadIdx.x;
  const int stride = gridDim.x * 256;
  for (; i < n4; i += stride) {
    fv4 v = reinterpret_cast<const fv4*>(in)[i];
    u16v4 p;
#pragma unroll
    for (int j = 0; j < 4; ++j) p[j] = f2h(v[j]);
    reinterpret_cast<u16v4*>(outp)[i] = p;
  }
}

// ---------------- C = A @ B^T, fp16 MFMA, gload_lds, wide wave tile ----------------
// Block tile 256(M) x 128(N), 4 waves (2Mx2N), wave tile 128x64: 32 MFMA per
// 12 ds_read_b128 per phase. 3 buffers, depth-2 prefetch, vmcnt(6) counted (T4).
// Swizzle (rule #21, verified 0-conflict r13): inverse-swz global source
// (chunk ^ (row>>1)&3) + swz ds_read. QKV=1: fp16 out to {Q,K,V} by col group.
template <int QKV>
__global__ __launch_bounds__(256, 2) void gemm_bt(
    const _Float16* __restrict__ A16, const _Float16* __restrict__ B16,
    float* __restrict__ C, const float* __restrict__ bias,
    unsigned short* __restrict__ Oq, unsigned short* __restrict__ Ok,
    unsigned short* __restrict__ Ov, int M, int NTILES, int K) {
  __shared__ _Float16 sA[3][8192];  // 256 rows x 32 k
  __shared__ _Float16 sB[3][4096];  // 128 rows x 32 k
  const int tid = threadIdx.x;
  const int lane = tid & 63;
  const int wv = tid >> 6;
  const int wr = wv >> 1, wc = wv & 1;
  const int g = lane >> 4, ln16 = lane & 15;

  // T1 XCD swizzle: all NTILES N-tiles of one M-panel share one XCD.
  const int hw = blockIdx.x;
  const int xcd = hw & 7;
  const int rem = hw >> 3;
  const int ntile = rem % NTILES;
  const int yhi = rem / NTILES;
  const int mtile = yhi * 8 + xcd;       // M/256 = 128 tiles, bijective
  const int mBase = mtile * 256;
  const int nBase = ntile * 128;

  fv4 acc[8][4] = {};

  // staging: lane l -> row_in_16 = l>>2; LDS chunk l&3 holds global chunk
  // (l&3) ^ ((l>>3)&3)  (= (row>>1)&3 since row bases are multiples of 16).
  const int srow = lane >> 2;
  const int cgx = ((lane & 3) ^ ((lane >> 3) & 3)) * 8;
  const long aStageBase = (long)(mBase + wv * 64 + srow) * K + cgx;  // 4 issues x 16 rows
  const long bStageBase = (long)(nBase + wv * 32 + srow) * K + cgx;  // 2 issues x 16 rows
  // frag reads: global chunk g of row r lives at LDS chunk g ^ ((ln16>>1)&3)
  const int rgx = (g ^ ((ln16 >> 1) & 3)) * 8;
  const int arow0 = wr * 128 + ln16;
  const int brow0 = wc * 64 + ln16;

  auto STAGE = [&](int t, int bi) {
#pragma unroll
    for (int i = 0; i < 4; ++i)
      __builtin_amdgcn_global_load_lds(
          (const __attribute__((address_space(1))) void*)(A16 + aStageBase + (long)i * 16 * K + t * 32),
          (__attribute__((address_space(3))) void*)&sA[bi][wv * 2048 + i * 512], 16, 0, 0);
#pragma unroll
    for (int i = 0; i < 2; ++i)
      __builtin_amdgcn_global_load_lds(
          (const __attribute__((address_space(1))) void*)(B16 + bStageBase + (long)i * 16 * K + t * 32),
          (__attribute__((address_space(3))) void*)&sB[bi][wv * 1024 + i * 512], 16, 0, 0);
  };
  auto COMPUTE = [&](int bi) {
    hfv8 fa[8], fb[4];
#pragma unroll
    for (int i = 0; i < 8; ++i)
      fa[i] = *(const hfv8*)&sA[bi][(arow0 + i * 16) * 32 + rgx];
#pragma unroll
    for (int j = 0; j < 4; ++j)
      fb[j] = *(const hfv8*)&sB[bi][(brow0 + j * 16) * 32 + rgx];
#pragma unroll
    for (int i = 0; i < 8; ++i)
#pragma unroll
      for (int j = 0; j < 4; ++j)
        acc[i][j] = __builtin_amdgcn_mfma_f32_16x16x32_f16(fa[i], fb[j], acc[i][j], 0, 0, 0);
  };

  const int NT = K / 32;  // 32
  STAGE(0, 0);
  STAGE(1, 1);
  for (int t = 0; t < NT; ++t) {
    if (t < NT - 1)
      asm volatile("s_waitcnt vmcnt(6)" ::: "memory");  // stage t landed; t+1 in flight
    else
      asm volatile("s_waitcnt vmcnt(0)" ::: "memory");
    __builtin_amdgcn_s_barrier();                        // all waves' stage t visible
    if (t + 2 < NT) STAGE(t + 2, (t + 2) % 3);           // buf last read at t-1: safe
    COMPUTE(t % 3);
    asm volatile("s_waitcnt lgkmcnt(0)" ::: "memory");   // reads retired before next barrier
  }

  // C/D layout (m89): col = lane&15, row = 4*(lane>>4) + reg (within 16x16)
  const int crow0 = mBase + wr * 128 + ((lane >> 4) << 2);
  const int ccol0 = nBase + wc * 64 + (lane & 15);
  if (QKV) {
    const int which = nBase >> 10;  // 0=Q 1=K 2=V, uniform per block
    unsigned short* outs = (which == 0) ? Oq : (which == 1) ? Ok : Ov;
    const int colb = ccol0 & 1023;
#pragma unroll
    for (int j = 0; j < 4; ++j) {
      const int col = colb + j * 16;
#pragma unroll
      for (int i = 0; i < 8; ++i) {
        const long rb = (long)(crow0 + i * 16) * 1024 + col;
#pragma unroll
        for (int r = 0; r < 4; ++r)
          outs[rb + (long)r * 1024] = f2h(acc[i][j][r]);
      }
    }
  } else {
    float bv[4];
#pragma unroll
    for (int j = 0; j < 4; ++j) bv[j] = bias ? bias[ccol0 + j * 16] : 0.f;
#pragma unroll
    for (int j = 0; j < 4; ++j) {
      const int col = ccol0 + j * 16;
#pragma unroll
      for (int i = 0; i < 8; ++i) {
        const long rb = (long)(crow0 + i * 16) * 1024 + col;
#pragma unroll
        for (int r = 0; r < 4; ++r)
          C[rb + (long)r * 1024] = acc[i][j][r] + bv[j];
      }
    }
  }
}

// ---------------- per-(b,seg,h) outer products: U = akT.v, ak split fp16 ----------------
__global__ __launch_bounds__(256) void seg_outer_mfma(
    const unsigned short* __restrict__ K16, const unsigned short* __restrict__ V16,
    float* __restrict__ U, float* __restrict__ Zs) {
  __shared__ _Float16 sAh[64 * 64], sAl[64 * 64];  // akT [d][s]
  __shared__ _Float16 sVh[64 * 64];                // vT  [e][s]
  __shared__ float sZf[64];
  const int bid = blockIdx.x;  // b*256 + seg*16 + h
  const int b = bid >> 8, seg = (bid >> 4) & 15, h = bid & 15;
  const int tid = threadIdx.x;
  const int lane = tid & 63, w = tid >> 6;
  const int g = lane >> 4, ln16 = lane & 15;
  const long base = ((long)b * L_DIM + (long)seg * SEG_S) * D_DIM + h * 64;

  if (tid < 64) sZf[tid] = 0.f;
  fv4 acc[4] = {};
  float zacc = 0.f;
  const int strow = tid & 63;
  const int sg0 = (tid >> 6) * 16;
  const int wsw = (strow & 7) << 3;
  const int rsw = (ln16 & 7) << 3;

  for (int c = 0; c < 8; ++c) {
    __syncthreads();
#pragma unroll
    for (int jj = 0; jj < 2; ++jj) {
      u16v8 ah, al, vh;
#pragma unroll
      for (int i = 0; i < 8; ++i) {
        const long gidx = base + (long)(c * 64 + sg0 + jj * 8 + i) * D_DIM + strow;
        const float kv = h2f(K16[gidx]);
        const float a = kv > 0.f ? kv + 1.f : __expf(kv);
        zacc += a;
        const unsigned short hb = f2h(a);
        ah[i] = hb;
        al[i] = f2h(a - h2f(hb));
        vh[i] = V16[gidx];
      }
      const int col = (sg0 + jj * 8) ^ wsw;
      *(u16v8*)&sAh[strow * 64 + col] = ah;
      *(u16v8*)&sAl[strow * 64 + col] = al;
      *(u16v8*)&sVh[strow * 64 + col] = vh;
    }
    __syncthreads();
#pragma unroll
    for (int kf = 0; kf < 2; ++kf) {
      const int so = (kf * 32 + g * 8) ^ rsw;
      hfv8 aH = *(const hfv8*)&sAh[(w * 16 + ln16) * 64 + so];
      hfv8 aL = *(const hfv8*)&sAl[(w * 16 + ln16) * 64 + so];
#pragma unroll
      for (int et = 0; et < 4; ++et) {
        hfv8 bH = *(const hfv8*)&sVh[(et * 16 + ln16) * 64 + so];
        acc[et] = __builtin_amdgcn_mfma_f32_16x16x32_f16(aH, bH, acc[et], 0, 0, 0);
        acc[et] = __builtin_amdgcn_mfma_f32_16x16x32_f16(aL, bH, acc[et], 0, 0, 0);
      }
    }
  }
  atomicAdd(&sZf[strow], zacc);
  __syncthreads();

  const long ub = (long)bid * 4096;
#pragma unroll
  for (int et = 0; et < 4; ++et)
#pragma unroll
    for (int r = 0; r < 4; ++r)
      U[ub + (long)(w * 16 + g * 4 + r) * 64 + et * 16 + ln16] = acc[et][r];
  if (tid < 64) Zs[(long)bid * 64 + tid] = sZf[tid];
}

// ---------------- exclusive prefix over segments (per b,h) ----------------
__global__ __launch_bounds__(256) void seg_prefix(
    const float* __restrict__ U, const float* __restrict__ Zs,
    float* __restrict__ Mem, float* __restrict__ Zp) {
  const int bh = blockIdx.x;
  const int b = bh >> 4, h = bh & 15;
  const int jc = blockIdx.y;
  const int tid = threadIdx.x;
  for (int j = jc * 512 + tid; j < jc * 512 + 512; j += 256) {
    float run = 0.f;
#pragma unroll
    for (int t = 0; t < NSEG; ++t) {
      const long idx = ((long)(b * 256 + t * 16 + h)) * 4096 + j;
      Mem[idx] = run;
      run += U[idx];
    }
  }
  if (jc == 0 && tid < 64) {
    float run = 0.f;
#pragma unroll
    for (int t = 0; t < NSEG; ++t) {
      const long idx = ((long)(b * 256 + t * 16 + h)) * 64 + tid;
      Zp[idx] = run;
      run += Zs[idx];
    }
  }
}

// ---------------- MFMA segment attention, all-fp16, batch-fused ----------------
__global__ __launch_bounds__(512, 4) void attn_seg_mfma(
    const unsigned short* __restrict__ Q16, const unsigned short* __restrict__ K16,
    const unsigned short* __restrict__ V16, const int* __restrict__ mask,
    const float* __restrict__ Mem, const float* __restrict__ Zp,
    const float* __restrict__ betas, unsigned short* __restrict__ Op16) {
  __shared__ _Float16 sKh[64 * 72];   // K chunk [key][d]; later Mem^T [e][d]
  __shared__ _Float16 sVTh[64 * 64];  // V^T [e][key], swizzled
  __shared__ _Float16 sP[8][16 * 72]; // per-wave P fp16 [q][key]
  __shared__ float sMadd[64], sZ[64], sGate[64];

  // T1 bijective XCD swizzle over 4096 blocks; the 4 qblks of one (b,seg,h)
  // (sharing K/V) land on the same XCD.
  const int bx = (blockIdx.x & 7) * 512 + (blockIdx.x >> 3);
  const int qblk = bx & 3, h = (bx >> 2) & 15, seg = (bx >> 6) & 15, b = bx >> 10;
  const int shb = b * 256 + seg * 16 + h;
  const int tid = threadIdx.x;
  const int lane = tid & 63, w = tid >> 6;
  const int g = lane >> 4, ln16 = lane & 15;
  const int rsw = (ln16 & 7) << 3;

  const int qglob = b * L_DIM + seg * SEG_S + qblk * 128 + w * 16 + ln16;
  const long qbase = (long)qglob * D_DIM + h * 64;
  hfv8 qh[2];
#pragma unroll
  for (int dt = 0; dt < 2; ++dt)
    qh[dt] = *(const hfv8*)&Q16[qbase + dt * 32 + g * 8];

  fv4 O[4] = {};
  float m_run = -1e30f, l_run = 0.f;
  const long kvbase0 = ((long)b * L_DIM + (long)seg * SEG_S) * D_DIM + h * 64;

  for (int c = 0; c < 8; ++c) {
    __syncthreads();
    {  // stage K [64 key][64 d]: 512 thr x 8 elems (pure u16v8 copy)
      const int row = tid >> 3, d0 = (tid & 7) * 8;
      const long ga = kvbase0 + (long)(c * 64 + row) * D_DIM + d0;
      *(u16v8*)&sKh[row * 72 + d0] = *(const u16v8*)&K16[ga];
    }
    {  // stage V^T [64 e][64 key], XOR-swizzled
      const int e = tid & 63, kg = (tid >> 6) * 8;
      u16v8 hv;
#pragma unroll
      for (int j = 0; j < 8; ++j)
        hv[j] = V16[kvbase0 + (long)(c * 64 + kg + j) * D_DIM + e];
      *(u16v8*)&sVTh[e * 64 + (kg ^ ((e & 7) << 3))] = hv;
    }
    if (tid < 64)
      sMadd[tid] = (mask[b * L_DIM + seg * SEG_S + c * 64 + tid] == 0) ? -1e9f : 0.f;
    __syncthreads();

    fv4 madd[4];
#pragma unroll
    for (int kt = 0; kt < 4; ++kt) madd[kt] = *(const fv4*)&sMadd[kt * 16 + g * 4];

    // S^T = K . Q
    fv4 sc[4];
#pragma unroll
    for (int kt = 0; kt < 4; ++kt) {
      const int ro = (kt * 16 + ln16) * 72 + g * 8;
      hfv8 kh0 = *(const hfv8*)&sKh[ro], kh1 = *(const hfv8*)&sKh[ro + 32];
      fv4 s = {};
      s = __builtin_amdgcn_mfma_f32_16x16x32_f16(kh0, qh[0], s, 0, 0, 0);
      s = __builtin_amdgcn_mfma_f32_16x16x32_f16(kh1, qh[1], s, 0, 0, 0);
      sc[kt] = s;
    }
    // online softmax (defer-max THR=8)
    float pmax = -3.0e38f;
#pragma unroll
    for (int kt = 0; kt < 4; ++kt)
#pragma unroll
      for (int r = 0; r < 4; ++r) {
        const float v = __builtin_fmaf(sc[kt][r], 0.125f, madd[kt][r]);
        sc[kt][r] = v;
        pmax = fmaxf(pmax, v);
      }
    pmax = fmaxf(pmax, __shfl_xor(pmax, 16));
    pmax = fmaxf(pmax, __shfl_xor(pmax, 32));
    if (pmax > m_run + 8.f) {
      const float resc = __expf(m_run - pmax);
      l_run *= resc;
#pragma unroll
      for (int et = 0; et < 4; ++et)
#pragma unroll
        for (int r = 0; r < 4; ++r) O[et][r] *= resc;
      m_run = pmax;
    }
    float psum = 0.f;
#pragma unroll
    for (int kt = 0; kt < 4; ++kt) {
      u16v4 pv;
#pragma unroll
      for (int r = 0; r < 4; ++r) {
        const unsigned short hb = f2h(__expf(sc[kt][r] - m_run));
        pv[r] = hb;
        psum += h2f(hb);
      }
      *(u16v4*)&sP[w][ln16 * 72 + kt * 16 + g * 4] = pv;
    }
    psum += __shfl_xor(psum, 16);
    psum += __shfl_xor(psum, 32);
    l_run += psum;

    hfv8 pf0 = *(const hfv8*)&sP[w][ln16 * 72 + g * 8];
    hfv8 pf1 = *(const hfv8*)&sP[w][ln16 * 72 + 32 + g * 8];
    // O^T += V^T . P
#pragma unroll
    for (int et = 0; et < 4; ++et) {
      const int rb = (et * 16 + ln16) * 64;
      hfv8 vh0 = *(const hfv8*)&sVTh[rb + ((g * 8) ^ rsw)];
      hfv8 vh1 = *(const hfv8*)&sVTh[rb + ((g * 8 + 32) ^ rsw)];
      fv4 o = O[et];
      o = __builtin_amdgcn_mfma_f32_16x16x32_f16(vh0, pf0, o, 0, 0, 0);
      o = __builtin_amdgcn_mfma_f32_16x16x32_f16(vh1, pf1, o, 0, 0, 0);
      O[et] = o;
    }
  }

  // ---- memory-read term ----
  __syncthreads();
  {  // stage Mem^T [e][d] into sKh
    const int e2 = (tid & 31) * 2, d4 = (tid >> 5) * 4;
    const float* Memp = Mem + (long)shb * 4096;
    fv2 ld[4];
#pragma unroll
    for (int i = 0; i < 4; ++i) ld[i] = *(const fv2*)&Memp[(d4 + i) * 64 + e2];
#pragma unroll
    for (int je = 0; je < 2; ++je) {
      u16v4 hv;
#pragma unroll
      for (int i = 0; i < 4; ++i) hv[i] = f2h(ld[i][je]);
      *(u16v4*)&sKh[(e2 + je) * 72 + d4] = hv;
    }
  }
  if (tid < 64) {
    sZ[tid] = Zp[(long)shb * 64 + tid];
    sGate[tid] = 1.f / (1.f + __expf(-betas[h * 64 + tid]));
  }
  __syncthreads();

  // aq = elu(q)+1 (fp16 single); denom = aq . z (fp32)
  float dpart = 0.f;
#pragma unroll
  for (int dt = 0; dt < 2; ++dt) {
    u16v8 ah;
#pragma unroll
    for (int j = 0; j < 8; ++j) {
      const float x = (float)qh[dt][j];
      const float a = x > 0.f ? x + 1.f : __expf(x);
      dpart += a * sZ[dt * 32 + g * 8 + j];
      ah[j] = f2h(a);
    }
    qh[dt] = __builtin_bit_cast(hfv8, ah);
  }
  dpart += __shfl_xor(dpart, 16);
  dpart += __shfl_xor(dpart, 32);
  const float invden = 1.f / (dpart + 1e-9f);
  const float invl = 1.f / l_run;

  const long obase = (long)qglob * D_DIM + h * 64;
#pragma unroll
  for (int et = 0; et < 4; ++et) {
    const int ro = (et * 16 + ln16) * 72 + g * 8;
    hfv8 mh0 = *(const hfv8*)&sKh[ro], mh1 = *(const hfv8*)&sKh[ro + 32];
    fv4 o = {};
    o = __builtin_amdgcn_mfma_f32_16x16x32_f16(mh0, qh[0], o, 0, 0, 0);
    o = __builtin_amdgcn_mfma_f32_16x16x32_f16(mh1, qh[1], o, 0, 0, 0);
    const fv4 gt = *(const fv4*)&sGate[et * 16 + g * 4];
    u16v4 st;
#pragma unroll
    for (int r = 0; r < 4; ++r) {
      const float att = gt[r] * o[r] * invden + (1.f - gt[r]) * O[et][r] * invl;
      st[r] = f2h(att);
    }
    *(u16v4*)&Op16[obase + et * 16 + g * 4] = st;
  }
}

// ---------------- host launch ----------------
extern "C" void kernel_launch(void* const* d_in, const int* in_sizes, int n_in,
                              void* d_out, int out_size, void* d_ws, size_t ws_size,
                              hipStream_t stream) {
  (void)in_sizes; (void)n_in; (void)out_size;
  const float* x     = (const float*)d_in[0];
  const int*   mask  = (const int*)d_in[1];
  const float* wq    = (const float*)d_in[2];
  const float* wk    = (const float*)d_in[3];
  const float* wv    = (const float*)d_in[4];
  const float* wo    = (const float*)d_in[5];
  const float* wob   = (const float*)d_in[6];
  const float* betas = (const float*)d_in[7];
  float* out = (float*)d_out;

  const size_t TOK = (size_t)M_TOK * D_DIM;  // 33.5M elements
  char* ws = (char*)d_ws;
  size_t off = 0;
  auto alloc = [&](size_t bytes) {
    char* p = ws + off;
    off += (bytes + 255) & ~(size_t)255;
    return p;
  };
  unsigned short* wqkv16 = (unsigned short*)alloc((size_t)3 * D_DIM * D_DIM * 2);
  unsigned short* wo16   = (unsigned short*)alloc((size_t)D_DIM * D_DIM * 2);
  unsigned short* x16 = (unsigned short*)alloc(TOK * 2);  // 64 MiB
  unsigned short* q16 = (unsigned short*)alloc(TOK * 2);
  unsigned short* k16 = (unsigned short*)alloc(TOK * 2);
  unsigned short* v16 = (unsigned short*)alloc(TOK * 2);
  float* U   = (float*)alloc((size_t)B_DIM * NSEG * H_NUM * 4096 * 4);
  float* Mem = (float*)alloc((size_t)B_DIM * NSEG * H_NUM * 4096 * 4);
  float* Zs  = (float*)alloc((size_t)B_DIM * NSEG * H_NUM * 64 * 4);
  float* Zp  = (float*)alloc((size_t)B_DIM * NSEG * H_NUM * 64 * 4);
  unsigned short* att16 = x16;  // x16 dead after QKV GEMM — reuse

  if (off > ws_size) return;

  conv_w16<<<256, 256, 0, stream>>>(wq, wqkv16, D_DIM * D_DIM / 4);
  conv_w16<<<256, 256, 0, stream>>>(wk, wqkv16 + (size_t)D_DIM * D_DIM, D_DIM * D_DIM / 4);
  conv_w16<<<256, 256, 0, stream>>>(wv, wqkv16 + (size_t)2 * D_DIM * D_DIM, D_DIM * D_DIM / 4);
  conv_w16<<<256, 256, 0, stream>>>(wo, wo16, D_DIM * D_DIM / 4);
  conv_w16<<<2048, 256, 0, stream>>>(x, x16, (int)(TOK / 4));

  // merged QKV: block tile 256x128, N = 3072 -> 24 N-tiles, 128 M-tiles
  const int qkvGrid = 24 * (M_TOK / 256);  // 3072 blocks
  gemm_bt<1><<<qkvGrid, 256, 0, stream>>>(
      (const _Float16*)x16, (const _Float16*)wqkv16, nullptr, nullptr,
      q16, k16, v16, M_TOK, 24, D_DIM);

  seg_outer_mfma<<<B_DIM * NSEG * H_NUM, 256, 0, stream>>>(k16, v16, U, Zs);
  seg_prefix<<<dim3(B_DIM * H_NUM, 8), 256, 0, stream>>>(U, Zs, Mem, Zp);

  attn_seg_mfma<<<B_DIM * NSEG * H_NUM * 4, 512, 0, stream>>>(
      q16, k16, v16, mask, Mem, Zp, betas, att16);

  const int oGrid = 8 * (M_TOK / 256);  // 1024 blocks
  gemm_bt<0><<<oGrid, 256, 0, stream>>>(
      (const _Float16*)att16, (const _Float16*)wo16, out, wob,
      nullptr, nullptr, nullptr, M_TOK, 8, D_DIM);
}